// Round 3
// baseline (203.271 us; speedup 1.0000x reference)
//
#include <hip/hip_runtime.h>
#include <hip/hip_bf16.h>

// Problem constants (fixed by reference)
#define DIMC 1024
#define HEADS 16
#define HEAD_DIM 64
#define KWIN 13
#define NSH 6
#define LSEQ 4096
#define BATCH 2
#define NROWS (BATCH*LSEQ)        // 8192 token rows
#define QKV_N (3*DIMC)            // 3072
#define SCALE_Q 0.125f            // 64^-0.5

#define TBLK 256                  // tokens per natten block
#define WROWS 268                 // staged K/V window rows (256 + 12)

typedef __attribute__((ext_vector_type(4))) float f32x4;
typedef __attribute__((ext_vector_type(8))) short bf16x8;

__device__ __forceinline__ void gload_lds16(const void* g, void* l) {
  __builtin_amdgcn_global_load_lds(
      (const __attribute__((address_space(1))) void*)g,
      (__attribute__((address_space(3))) void*)l, 16, 0, 0);
}

// unpack 8 bf16 (in uint4) -> 8 f32
__device__ __forceinline__ void cvt8(uint4 r, float* f) {
  unsigned u[4] = {r.x, r.y, r.z, r.w};
#pragma unroll
  for (int w = 0; w < 4; w++) {
    f[2*w]   = __uint_as_float(u[w] << 16);
    f[2*w+1] = __uint_as_float(u[w] & 0xffff0000u);
  }
}

// ---------------- cast fp32 -> bf16 (vectorized) ----------------
__global__ __launch_bounds__(256) void cast_kernel(const float* __restrict__ in,
                                                   __hip_bfloat16* __restrict__ out,
                                                   int n4) {
  int i = blockIdx.x * 256 + threadIdx.x;
  if (i >= n4) return;
  float4 v = ((const float4*)in)[i];
  union { short4 s; __hip_bfloat16 h[4]; } u;
  u.h[0] = __float2bfloat16(v.x);
  u.h[1] = __float2bfloat16(v.y);
  u.h[2] = __float2bfloat16(v.z);
  u.h[3] = __float2bfloat16(v.w);
  ((short4*)out)[i] = u.s;
}

// =======================================================================
// 256x256 8-phase bf16 GEMM (T2 swizzle + T3/T4 counted vmcnt + T5 setprio)
// C[M][N] = A[M][K] * B[N][K]^T + bias, bf16 out. 512 thr = 8 waves (2Mx4N).
// =======================================================================
#define PH_MID do { __builtin_amdgcn_s_barrier(); \
  asm volatile("s_waitcnt lgkmcnt(0)" ::: "memory"); \
  __builtin_amdgcn_sched_barrier(0); \
  __builtin_amdgcn_s_setprio(1); } while (0)
#define PH_END do { __builtin_amdgcn_s_setprio(0); \
  __builtin_amdgcn_s_barrier(); } while (0)
#define VMW4 do { asm volatile("s_waitcnt vmcnt(4)" ::: "memory"); \
  __builtin_amdgcn_sched_barrier(0); } while (0)

// stage: 2 gload_lds of 1KB; LDS dest linear; global source pre-swizzled
#define STG(gptr, ldsoff) do { \
  gload_lds16((const void*)(gptr),      (void*)(smem + (ldsoff) + w * 2048)); \
  gload_lds16((const void*)((gptr)+q8), (void*)(smem + (ldsoff) + w * 2048 + 1024)); \
} while (0)
#define STAGE_A(buf, h, t) STG(((h) ? gA1 : gA0) + (size_t)(t) * 64, (buf)*32768 + (h)*16384)
#define STAGE_B(buf, h, t) STG(((h) ? gB1 : gB0) + (size_t)(t) * 64, 65536 + (buf)*32768 + (h)*16384)

#define LD_A4(buf, mb) do { _Pragma("unroll") for (int mm = 0; mm < 4; mm++) { \
    const char* p_ = smem + (buf)*32768 + (rA + ((mb) + mm) * 16) * 128; \
    afr[mm][0] = *(const bf16x8*)(p_ + ck0); \
    afr[mm][1] = *(const bf16x8*)(p_ + ck1); } } while (0)
#define LD_B2(buf, nb, dst) do { _Pragma("unroll") for (int nn = 0; nn < 2; nn++) { \
    const char* p_ = smem + 65536 + (buf)*32768 + (rB + ((nb) + nn) * 16) * 128; \
    dst[nn][0] = *(const bf16x8*)(p_ + ck0); \
    dst[nn][1] = *(const bf16x8*)(p_ + ck1); } } while (0)
#define MM16(mb, bsel, bf) do { _Pragma("unroll") for (int mm = 0; mm < 4; mm++) \
  _Pragma("unroll") for (int nn = 0; nn < 2; nn++) { \
    acc[(mb)+mm][(bsel)*2+nn] = __builtin_amdgcn_mfma_f32_16x16x32_bf16(afr[mm][0], bf[nn][0], acc[(mb)+mm][(bsel)*2+nn], 0, 0, 0); \
    acc[(mb)+mm][(bsel)*2+nn] = __builtin_amdgcn_mfma_f32_16x16x32_bf16(afr[mm][1], bf[nn][1], acc[(mb)+mm][(bsel)*2+nn], 0, 0, 0); } } while (0)

__global__ __launch_bounds__(512, 2) void gemm8(const __hip_bfloat16* __restrict__ A,
                                                const __hip_bfloat16* __restrict__ B,
                                                const float* __restrict__ bias,
                                                __hip_bfloat16* __restrict__ C,
                                                int M, int N, int K) {
  __shared__ __align__(16) char smem[131072];
  const int tid  = threadIdx.x;
  const int lane = tid & 63;
  const int w    = tid >> 6;     // 0..7
  const int wm   = w >> 2;       // 0..1
  const int wn   = w & 3;        // 0..3
  const int fr   = lane & 15;
  const int fq   = (lane >> 4) & 3;

  // bijective XCD swizzle (nwg % 8 handled generally, m204 form)
  int id = blockIdx.x;
  {
    const int nwg = gridDim.x;
    const int qq = nwg >> 3, rr = nwg & 7;
    const int xcd = id & 7, off = id >> 3;
    id = (xcd < rr ? xcd * (qq + 1) : rr * (qq + 1) + (xcd - rr) * qq) + off;
  }
  const int nbx = N >> 8;
  const int bx = id % nbx, by = id / nbx;
  const int m0 = by << 8, n0 = bx << 8;

  // staging source: lane covers row (h*128 + w*16 + (lane>>3) [+8 for call 2]),
  // global chunk g = (lane&7) ^ (row&7) (inverse of the read-side XOR swizzle)
  const int srow = w * 16 + (lane >> 3);
  const int gch  = ((lane & 7) ^ (lane >> 3)) * 8;
  const __hip_bfloat16* gA0 = A + (size_t)(m0 + srow) * K + gch;
  const __hip_bfloat16* gA1 = A + (size_t)(m0 + 128 + srow) * K + gch;
  const __hip_bfloat16* gB0 = B + (size_t)(n0 + srow) * K + gch;
  const __hip_bfloat16* gB1 = B + (size_t)(n0 + 128 + srow) * K + gch;
  const size_t q8 = (size_t)8 * K;

  // fragment read addressing (swizzled): byte = row*128 + ((ks*4+fq)^(row&7))*16
  const int rA  = wm * 128 + fr;
  const int rB  = wn * 64 + fr;
  const int ck0 = ((fq)     ^ (fr & 7)) * 16;
  const int ck1 = ((4 | fq) ^ (fr & 7)) * 16;

  f32x4 acc[8][4] = {};
  bf16x8 afr[4][2], bfr0[2][2], bfr1[2][2];

  // prologue: tile0 A+B, tile1 B  (12 per-wave loads; drain to tile0 complete)
  STAGE_A(0, 0, 0); STAGE_A(0, 1, 0);
  STAGE_B(0, 0, 0); STAGE_B(0, 1, 0);
  STAGE_B(1, 0, 1); STAGE_B(1, 1, 1);
  VMW4;
  __builtin_amdgcn_s_barrier();

  const int NT = K >> 6;
  const int NI = NT >> 1;
#pragma unroll 1
  for (int i = 0; i < NI; i++) {
    const int t1 = (2*i+1 < NT) ? 2*i+1 : NT-1;
    const int t2 = (2*i+2 < NT) ? 2*i+2 : NT-1;
    const int t3 = (2*i+3 < NT) ? 2*i+3 : NT-1;
    // p0
    LD_A4(0, 0); LD_B2(0, 0, bfr0);
    STAGE_A(1, 0, t1);
    PH_MID; MM16(0, 0, bfr0); PH_END;
    // p1
    LD_B2(0, 2, bfr1);
    STAGE_A(1, 1, t1);
    PH_MID; MM16(0, 1, bfr1); PH_END;
    // p2
    LD_A4(0, 4);
    STAGE_B(0, 0, t2);
    PH_MID; MM16(4, 0, bfr0); PH_END;
    // p3
    STAGE_B(0, 1, t2);
    VMW4;
    PH_MID; MM16(4, 1, bfr1); PH_END;
    // p4
    LD_A4(1, 0); LD_B2(1, 0, bfr0);
    STAGE_A(0, 0, t2);
    PH_MID; MM16(0, 0, bfr0); PH_END;
    // p5
    LD_B2(1, 2, bfr1);
    STAGE_A(0, 1, t2);
    PH_MID; MM16(0, 1, bfr1); PH_END;
    // p6
    LD_A4(1, 4);
    STAGE_B(1, 0, t3);
    PH_MID; MM16(4, 0, bfr0); PH_END;
    // p7
    STAGE_B(1, 1, t3);
    VMW4;
    PH_MID; MM16(4, 1, bfr1); PH_END;
  }

  // epilogue: drain stray stages, then LDS-transpose for coalesced bf16 stores
  asm volatile("s_waitcnt vmcnt(0)" ::: "memory");
  __builtin_amdgcn_sched_barrier(0);
  __builtin_amdgcn_s_barrier();

  float* sf = (float*)(smem) + w * 1088;       // 16 rows * 68 f32 per wave strip
  float bv[4];
#pragma unroll
  for (int n = 0; n < 4; n++) bv[n] = bias[n0 + wn * 64 + n * 16 + fr];

#pragma unroll 1
  for (int m = 0; m < 8; m++) {
#pragma unroll
    for (int n = 0; n < 4; n++)
#pragma unroll
      for (int i = 0; i < 4; i++)
        sf[(fq * 4 + i) * 68 + n * 16 + fr] = acc[m][n][i] + bv[n];
    // read back row-major: lane -> row fr, cols fq*16..fq*16+15
    float v[16];
#pragma unroll
    for (int e = 0; e < 16; e++) v[e] = sf[fr * 68 + fq * 16 + e];
    union { ushort us[16]; uint4 u4[2]; } o;
#pragma unroll
    for (int e = 0; e < 16; e++) {
      __hip_bfloat16 hb = __float2bfloat16(v[e]);
      o.us[e] = *(ushort*)&hb;
    }
    __hip_bfloat16* cp = C + (size_t)(m0 + wm * 128 + m * 16 + fr) * N + n0 + wn * 64 + fq * 16;
    *(uint4*)(cp)     = o.u4[0];
    *(uint4*)(cp + 8) = o.u4[1];
  }
}

// ---------------- bf16 GEMM 128^2 (kept for proj): C = A*B^T + bias ----------------
template<int OUT_BF16>
__global__ __launch_bounds__(256) void gemm_bt(const __hip_bfloat16* __restrict__ A,
                                               const __hip_bfloat16* __restrict__ B,
                                               const float* __restrict__ bias,
                                               void* __restrict__ Cout,
                                               int M, int N, int K) {
  __shared__ __align__(16) __hip_bfloat16 As[128 * 32];
  __shared__ __align__(16) __hip_bfloat16 Bs[128 * 32];

  const int tid  = threadIdx.x;
  const int lane = tid & 63;
  const int wave = tid >> 6;
  const int m0 = blockIdx.y * 128;
  const int n0 = blockIdx.x * 128;
  const int wr = wave >> 1;
  const int wc = wave & 1;

  f32x4 acc[4][4] = {};

  const int rA0  = wave * 32 + (lane >> 2);
  const int kcol = (lane & 3) * 8;
  const __hip_bfloat16* gA = A + (size_t)(m0 + rA0) * K + kcol;
  const __hip_bfloat16* gB = B + (size_t)(n0 + rA0) * K + kcol;
  __hip_bfloat16* lA0 = As + wave * 1024;
  __hip_bfloat16* lA1 = As + wave * 1024 + 512;
  __hip_bfloat16* lB0 = Bs + wave * 1024;
  __hip_bfloat16* lB1 = Bs + wave * 1024 + 512;

  const int fr = lane & 15;
  const int fk = (lane >> 4) * 8;

  for (int k0 = 0; k0 < K; k0 += 32) {
    gload_lds16(gA,                  lA0);
    gload_lds16(gA + (size_t)16 * K, lA1);
    gload_lds16(gB,                  lB0);
    gload_lds16(gB + (size_t)16 * K, lB1);
    gA += 32;
    gB += 32;
    __syncthreads();

    bf16x8 af[4], bfr[4];
#pragma unroll
    for (int i = 0; i < 4; i++)
      af[i] = *(const bf16x8*)&As[(wr * 64 + i * 16 + fr) * 32 + fk];
#pragma unroll
    for (int i = 0; i < 4; i++)
      bfr[i] = *(const bf16x8*)&Bs[(wc * 64 + i * 16 + fr) * 32 + fk];

#pragma unroll
    for (int mi = 0; mi < 4; mi++)
#pragma unroll
      for (int ni = 0; ni < 4; ni++)
        acc[mi][ni] = __builtin_amdgcn_mfma_f32_16x16x32_bf16(af[mi], bfr[ni], acc[mi][ni], 0, 0, 0);

    __syncthreads();
  }

#pragma unroll
  for (int ni = 0; ni < 4; ni++) {
    const int col = n0 + wc * 64 + ni * 16 + (lane & 15);
    const float bv = bias[col];
#pragma unroll
    for (int mi = 0; mi < 4; mi++) {
      const int row = m0 + wr * 64 + mi * 16 + ((lane >> 4) << 2);
#pragma unroll
      for (int i = 0; i < 4; i++) {
        const float v = acc[mi][ni][i] + bv;
        if (OUT_BF16)
          ((__hip_bfloat16*)Cout)[(size_t)(row + i) * N + col] = __float2bfloat16(v);
        else
          ((float*)Cout)[(size_t)(row + i) * N + col] = v;
      }
    }
  }
}

// ---------------- neighborhood attention: lane-per-token ----------------
__global__ __launch_bounds__(256, 2) void natten(const __hip_bfloat16* __restrict__ qkv,
                                                 const float* __restrict__ rpb,
                                                 __hip_bfloat16* __restrict__ att) {
  __shared__ __align__(16) unsigned char smem[2 * WROWS * 128];  // K then V, swizzled

  const int tid = threadIdx.x;
  const int tb  = blockIdx.x;
  const int h   = blockIdx.y;
  const int b   = blockIdx.z;
  const int t0  = tb * TBLK;

  int r0 = t0 - NSH;
  if (r0 < 0) r0 = 0;
  if (r0 > LSEQ - WROWS) r0 = LSEQ - WROWS;

  const __hip_bfloat16* kg = qkv + ((size_t)b * LSEQ + r0) * QKV_N + DIMC + h * HEAD_DIM;
  const __hip_bfloat16* vg = kg + DIMC;
#pragma unroll 1
  for (int i = tid; i < WROWS * 8; i += 256) {
    const int row = i >> 3, c = i & 7;
    const uint4 kk = *(const uint4*)(kg + (size_t)row * QKV_N + c * 8);
    const uint4 vv = *(const uint4*)(vg + (size_t)row * QKV_N + c * 8);
    const int off = row * 128 + ((c * 16) ^ ((row & 7) << 4));
    *(uint4*)(smem + off) = kk;
    *(uint4*)(smem + WROWS * 128 + off) = vv;
  }
  __syncthreads();

  const int t = t0 + tid;
  int ni = t - NSH;
  ni = ni < 0 ? 0 : (ni > LSEQ - KWIN ? LSEQ - KWIN : ni);
  const int rbase = ni - r0;
  const int pi = NSH + (t < NSH ? NSH - t : 0) + (t + NSH >= LSEQ ? LSEQ - t - 1 - NSH : 0);
  const float* rp = rpb + h * (2 * KWIN - 1) + pi;

  const __hip_bfloat16* qg = qkv + ((size_t)b * LSEQ + t) * QKV_N + h * HEAD_DIM;
  float qf[64];
#pragma unroll
  for (int c = 0; c < 8; c++) {
    uint4 qq = *(const uint4*)(qg + c * 8);
    cvt8(qq, qf + c * 8);
  }

  float p[KWIN];
#pragma unroll
  for (int j = 0; j < KWIN; j++) {
    const int row = rbase + j;
    const int sw = (row & 7) << 4;
    float s = 0.f;
#pragma unroll
    for (int c = 0; c < 8; c++) {
      uint4 kk = *(const uint4*)(smem + row * 128 + ((c * 16) ^ sw));
      float kf[8];
      cvt8(kk, kf);
#pragma unroll
      for (int e = 0; e < 8; e++) s += qf[c * 8 + e] * kf[e];
    }
    p[j] = s * SCALE_Q + rp[j];
  }

  float m = p[0];
#pragma unroll
  for (int j = 1; j < KWIN; j++) m = fmaxf(m, p[j]);
  float sum = 0.f;
#pragma unroll
  for (int j = 0; j < KWIN; j++) { p[j] = __expf(p[j] - m); sum += p[j]; }
  const float inv = 1.f / sum;
#pragma unroll
  for (int j = 0; j < KWIN; j++) p[j] *= inv;

  __hip_bfloat16* og = att + ((size_t)b * LSEQ + t) * DIMC + h * HEAD_DIM;
#pragma unroll
  for (int c = 0; c < 8; c++) {
    float acc[8] = {0.f, 0.f, 0.f, 0.f, 0.f, 0.f, 0.f, 0.f};
#pragma unroll
    for (int j = 0; j < KWIN; j++) {
      const int row = rbase + j;
      uint4 vv = *(const uint4*)(smem + WROWS * 128 + row * 128 + ((c * 16) ^ ((row & 7) << 4)));
      float vf[8];
      cvt8(vv, vf);
#pragma unroll
      for (int e = 0; e < 8; e++) acc[e] += p[j] * vf[e];
    }
    union { ushort us[8]; uint4 v; } o;
#pragma unroll
    for (int e = 0; e < 8; e++) {
      __hip_bfloat16 hb = __float2bfloat16(acc[e]);
      o.us[e] = *(ushort*)&hb;
    }
    *(uint4*)(og + c * 8) = o.v;
  }
}

// ---------------- launch ----------------
extern "C" void kernel_launch(void* const* d_in, const int* in_sizes, int n_in,
                              void* d_out, int out_size, void* d_ws, size_t ws_size,
                              hipStream_t stream) {
  const float* x      = (const float*)d_in[0];
  const float* qkv_w  = (const float*)d_in[1];
  const float* qkv_b  = (const float*)d_in[2];
  const float* rpb    = (const float*)d_in[3];
  const float* proj_w = (const float*)d_in[4];
  const float* proj_b = (const float*)d_in[5];
  float* out = (float*)d_out;

  char* ws = (char*)d_ws;
  __hip_bfloat16* xb    = (__hip_bfloat16*)(ws);
  __hip_bfloat16* wqkv  = (__hip_bfloat16*)(ws + 16777216);
  __hip_bfloat16* wproj = (__hip_bfloat16*)(ws + 23068672);
  __hip_bfloat16* qkv   = (__hip_bfloat16*)(ws + 25165824);
  __hip_bfloat16* att   = (__hip_bfloat16*)(ws + 75497472);

  cast_kernel<<<(NROWS * DIMC / 4 + 255) / 256, 256, 0, stream>>>(x, xb, NROWS * DIMC / 4);
  cast_kernel<<<(QKV_N * DIMC / 4 + 255) / 256, 256, 0, stream>>>(qkv_w, wqkv, QKV_N * DIMC / 4);
  cast_kernel<<<(DIMC * DIMC / 4 + 255) / 256, 256, 0, stream>>>(proj_w, wproj, DIMC * DIMC / 4);

  gemm8<<<(NROWS / 256) * (QKV_N / 256), 512, 0, stream>>>(
      xb, wqkv, qkv_b, qkv, NROWS, QKV_N, DIMC);

  natten<<<dim3(LSEQ / TBLK, HEADS, BATCH), 256, 0, stream>>>(qkv, rpb, att);

  gemm_bt<0><<<dim3(DIMC / 128, NROWS / 128), 256, 0, stream>>>(
      att, wproj, proj_b, (void*)out, NROWS, DIMC, DIMC);
}

// Round 4
// 202.516 us; speedup vs baseline: 1.0037x; 1.0037x over previous
//
#include <hip/hip_runtime.h>
#include <hip/hip_bf16.h>

// Problem constants (fixed by reference)
#define DIMC 1024
#define HEADS 16
#define HEAD_DIM 64
#define KWIN 13
#define NSH 6
#define LSEQ 4096
#define BATCH 2
#define NROWS (BATCH*LSEQ)        // 8192 token rows
#define QKV_N (3*DIMC)            // 3072
#define SCALE_Q 0.125f            // 64^-0.5

#define TBLK 256                  // tokens per natten block
#define WROWS 268                 // staged K/V window rows (256 + 12)

typedef __attribute__((ext_vector_type(4))) float f32x4;
typedef __attribute__((ext_vector_type(8))) short bf16x8;

__device__ __forceinline__ void gload_lds16(const void* g, void* l) {
  __builtin_amdgcn_global_load_lds(
      (const __attribute__((address_space(1))) void*)g,
      (__attribute__((address_space(3))) void*)l, 16, 0, 0);
}

// unpack 8 bf16 (in uint4) -> 8 f32
__device__ __forceinline__ void cvt8(uint4 r, float* f) {
  unsigned u[4] = {r.x, r.y, r.z, r.w};
#pragma unroll
  for (int w = 0; w < 4; w++) {
    f[2*w]   = __uint_as_float(u[w] << 16);
    f[2*w+1] = __uint_as_float(u[w] & 0xffff0000u);
  }
}

// ---------------- cast fp32 -> bf16 (vectorized) ----------------
__global__ __launch_bounds__(256) void cast_kernel(const float* __restrict__ in,
                                                   __hip_bfloat16* __restrict__ out,
                                                   int n4) {
  int i = blockIdx.x * 256 + threadIdx.x;
  if (i >= n4) return;
  float4 v = ((const float4*)in)[i];
  union { short4 s; __hip_bfloat16 h[4]; } u;
  u.h[0] = __float2bfloat16(v.x);
  u.h[1] = __float2bfloat16(v.y);
  u.h[2] = __float2bfloat16(v.z);
  u.h[3] = __float2bfloat16(v.w);
  ((short4*)out)[i] = u.s;
}

// =======================================================================
// 256x256 8-phase bf16 GEMM — de-walled (template-verbatim waits, no
// sched_barrier in the hot loop; m141 lesson).
// C[M][N] = A[M][K] * B[N][K]^T + bias, bf16 out. 512 thr = 8 waves (2Mx4N).
// =======================================================================
#define PH_MID do { __builtin_amdgcn_s_barrier(); \
  asm volatile("s_waitcnt lgkmcnt(0)"); \
  __builtin_amdgcn_s_setprio(1); } while (0)
#define PH_END do { __builtin_amdgcn_s_setprio(0); \
  __builtin_amdgcn_s_barrier(); } while (0)
#define VMW4 do { asm volatile("s_waitcnt vmcnt(4)"); } while (0)

// stage: 2 gload_lds of 1KB; LDS dest linear; global source pre-swizzled
#define STG(gptr, ldsoff) do { \
  gload_lds16((const void*)(gptr),      (void*)(smem + (ldsoff) + w * 2048)); \
  gload_lds16((const void*)((gptr)+q8), (void*)(smem + (ldsoff) + w * 2048 + 1024)); \
} while (0)
#define STAGE_A(buf, h, t) STG(((h) ? gA1 : gA0) + (size_t)(t) * 64, (buf)*32768 + (h)*16384)
#define STAGE_B(buf, h, t) STG(((h) ? gB1 : gB0) + (size_t)(t) * 64, 65536 + (buf)*32768 + (h)*16384)

#define LD_A4(buf, mb) do { _Pragma("unroll") for (int mm = 0; mm < 4; mm++) { \
    const char* p_ = smem + (buf)*32768 + (rA + ((mb) + mm) * 16) * 128; \
    afr[mm][0] = *(const bf16x8*)(p_ + ck0); \
    afr[mm][1] = *(const bf16x8*)(p_ + ck1); } } while (0)
#define LD_B2(buf, nb, dst) do { _Pragma("unroll") for (int nn = 0; nn < 2; nn++) { \
    const char* p_ = smem + 65536 + (buf)*32768 + (rB + ((nb) + nn) * 16) * 128; \
    dst[nn][0] = *(const bf16x8*)(p_ + ck0); \
    dst[nn][1] = *(const bf16x8*)(p_ + ck1); } } while (0)
#define MM16(mb, bsel, bf) do { _Pragma("unroll") for (int mm = 0; mm < 4; mm++) \
  _Pragma("unroll") for (int nn = 0; nn < 2; nn++) { \
    acc[(mb)+mm][(bsel)*2+nn] = __builtin_amdgcn_mfma_f32_16x16x32_bf16(afr[mm][0], bf[nn][0], acc[(mb)+mm][(bsel)*2+nn], 0, 0, 0); \
    acc[(mb)+mm][(bsel)*2+nn] = __builtin_amdgcn_mfma_f32_16x16x32_bf16(afr[mm][1], bf[nn][1], acc[(mb)+mm][(bsel)*2+nn], 0, 0, 0); } } while (0)

__global__ __launch_bounds__(512, 2) void gemm8(const __hip_bfloat16* __restrict__ A,
                                                const __hip_bfloat16* __restrict__ B,
                                                const float* __restrict__ bias,
                                                __hip_bfloat16* __restrict__ C,
                                                int M, int N, int K) {
  __shared__ __align__(16) char smem[131072];
  const int tid  = threadIdx.x;
  const int lane = tid & 63;
  const int w    = tid >> 6;     // 0..7
  const int wm   = w >> 2;       // 0..1
  const int wn   = w & 3;        // 0..3
  const int fr   = lane & 15;
  const int fq   = (lane >> 4) & 3;

  // bijective XCD swizzle
  int id = blockIdx.x;
  {
    const int nwg = gridDim.x;
    const int qq = nwg >> 3, rr = nwg & 7;
    const int xcd = id & 7, off = id >> 3;
    id = (xcd < rr ? xcd * (qq + 1) : rr * (qq + 1) + (xcd - rr) * qq) + off;
  }
  const int nbx = N >> 8;
  const int bx = id % nbx, by = id / nbx;
  const int m0 = by << 8, n0 = bx << 8;

  // staging source: lane covers row (h*128 + w*16 + (lane>>3) [+8 for call 2]),
  // global chunk g = (lane&7) ^ (row&7) (inverse of the read-side XOR swizzle)
  const int srow = w * 16 + (lane >> 3);
  const int gch  = ((lane & 7) ^ (lane >> 3)) * 8;
  const __hip_bfloat16* gA0 = A + (size_t)(m0 + srow) * K + gch;
  const __hip_bfloat16* gA1 = A + (size_t)(m0 + 128 + srow) * K + gch;
  const __hip_bfloat16* gB0 = B + (size_t)(n0 + srow) * K + gch;
  const __hip_bfloat16* gB1 = B + (size_t)(n0 + 128 + srow) * K + gch;
  const size_t q8 = (size_t)8 * K;

  // fragment read addressing (swizzled): byte = row*128 + ((ks*4+fq)^(row&7))*16
  const int rA  = wm * 128 + fr;
  const int rB  = wn * 64 + fr;
  const int ck0 = ((fq)     ^ (fr & 7)) * 16;
  const int ck1 = ((4 | fq) ^ (fr & 7)) * 16;

  f32x4 acc[8][4] = {};
  bf16x8 afr[4][2], bfr0[2][2], bfr1[2][2];

  // prologue: tile0 A+B, tile1 B  (12 per-wave loads; drain to tile0 complete)
  STAGE_A(0, 0, 0); STAGE_A(0, 1, 0);
  STAGE_B(0, 0, 0); STAGE_B(0, 1, 0);
  STAGE_B(1, 0, 1); STAGE_B(1, 1, 1);
  VMW4;
  __builtin_amdgcn_s_barrier();

  const int NT = K >> 6;
  const int NI = NT >> 1;
#pragma unroll 1
  for (int i = 0; i < NI; i++) {
    const int t1 = (2*i+1 < NT) ? 2*i+1 : NT-1;
    const int t2 = (2*i+2 < NT) ? 2*i+2 : NT-1;
    const int t3 = (2*i+3 < NT) ? 2*i+3 : NT-1;
    // p0
    LD_A4(0, 0); LD_B2(0, 0, bfr0);
    STAGE_A(1, 0, t1);
    PH_MID; MM16(0, 0, bfr0); PH_END;
    // p1
    LD_B2(0, 2, bfr1);
    STAGE_A(1, 1, t1);
    PH_MID; MM16(0, 1, bfr1); PH_END;
    // p2
    LD_A4(0, 4);
    STAGE_B(0, 0, t2);
    PH_MID; MM16(4, 0, bfr0); PH_END;
    // p3
    STAGE_B(0, 1, t2);
    VMW4;
    PH_MID; MM16(4, 1, bfr1); PH_END;
    // p4
    LD_A4(1, 0); LD_B2(1, 0, bfr0);
    STAGE_A(0, 0, t2);
    PH_MID; MM16(0, 0, bfr0); PH_END;
    // p5
    LD_B2(1, 2, bfr1);
    STAGE_A(0, 1, t2);
    PH_MID; MM16(0, 1, bfr1); PH_END;
    // p6
    LD_A4(1, 4);
    STAGE_B(1, 0, t3);
    PH_MID; MM16(4, 0, bfr0); PH_END;
    // p7
    STAGE_B(1, 1, t3);
    VMW4;
    PH_MID; MM16(4, 1, bfr1); PH_END;
  }

  // epilogue: drain stray stages (DMA-vs-LDS-reuse race is compiler-invisible:
  // keep the clobber here, once per kernel), then LDS-transpose stores
  asm volatile("s_waitcnt vmcnt(0)" ::: "memory");
  __builtin_amdgcn_s_barrier();

  float* sf = (float*)(smem) + w * 1088;       // 16 rows * 68 f32 per wave strip
  float bv[4];
#pragma unroll
  for (int n = 0; n < 4; n++) bv[n] = bias[n0 + wn * 64 + n * 16 + fr];

#pragma unroll 1
  for (int m = 0; m < 8; m++) {
#pragma unroll
    for (int n = 0; n < 4; n++)
#pragma unroll
      for (int i = 0; i < 4; i++)
        sf[(fq * 4 + i) * 68 + n * 16 + fr] = acc[m][n][i] + bv[n];
    float v[16];
#pragma unroll
    for (int e = 0; e < 16; e++) v[e] = sf[fr * 68 + fq * 16 + e];
    union { ushort us[16]; uint4 u4[2]; } o;
#pragma unroll
    for (int e = 0; e < 16; e++) {
      __hip_bfloat16 hb = __float2bfloat16(v[e]);
      o.us[e] = *(ushort*)&hb;
    }
    __hip_bfloat16* cp = C + (size_t)(m0 + wm * 128 + m * 16 + fr) * N + n0 + wn * 64 + fq * 16;
    *(uint4*)(cp)     = o.u4[0];
    *(uint4*)(cp + 8) = o.u4[1];
  }
}

// ---------------- bf16 GEMM 128^2 (proj): C = A*B^T + bias ----------------
template<int OUT_BF16>
__global__ __launch_bounds__(256) void gemm_bt(const __hip_bfloat16* __restrict__ A,
                                               const __hip_bfloat16* __restrict__ B,
                                               const float* __restrict__ bias,
                                               void* __restrict__ Cout,
                                               int M, int N, int K) {
  __shared__ __align__(16) __hip_bfloat16 As[128 * 32];
  __shared__ __align__(16) __hip_bfloat16 Bs[128 * 32];

  const int tid  = threadIdx.x;
  const int lane = tid & 63;
  const int wave = tid >> 6;
  const int m0 = blockIdx.y * 128;
  const int n0 = blockIdx.x * 128;
  const int wr = wave >> 1;
  const int wc = wave & 1;

  f32x4 acc[4][4] = {};

  const int rA0  = wave * 32 + (lane >> 2);
  const int kcol = (lane & 3) * 8;
  const __hip_bfloat16* gA = A + (size_t)(m0 + rA0) * K + kcol;
  const __hip_bfloat16* gB = B + (size_t)(n0 + rA0) * K + kcol;
  __hip_bfloat16* lA0 = As + wave * 1024;
  __hip_bfloat16* lA1 = As + wave * 1024 + 512;
  __hip_bfloat16* lB0 = Bs + wave * 1024;
  __hip_bfloat16* lB1 = Bs + wave * 1024 + 512;

  const int fr = lane & 15;
  const int fk = (lane >> 4) * 8;

  for (int k0 = 0; k0 < K; k0 += 32) {
    gload_lds16(gA,                  lA0);
    gload_lds16(gA + (size_t)16 * K, lA1);
    gload_lds16(gB,                  lB0);
    gload_lds16(gB + (size_t)16 * K, lB1);
    gA += 32;
    gB += 32;
    __syncthreads();

    bf16x8 af[4], bfr[4];
#pragma unroll
    for (int i = 0; i < 4; i++)
      af[i] = *(const bf16x8*)&As[(wr * 64 + i * 16 + fr) * 32 + fk];
#pragma unroll
    for (int i = 0; i < 4; i++)
      bfr[i] = *(const bf16x8*)&Bs[(wc * 64 + i * 16 + fr) * 32 + fk];

#pragma unroll
    for (int mi = 0; mi < 4; mi++)
#pragma unroll
      for (int ni = 0; ni < 4; ni++)
        acc[mi][ni] = __builtin_amdgcn_mfma_f32_16x16x32_bf16(af[mi], bfr[ni], acc[mi][ni], 0, 0, 0);

    __syncthreads();
  }

#pragma unroll
  for (int ni = 0; ni < 4; ni++) {
    const int col = n0 + wc * 64 + ni * 16 + (lane & 15);
    const float bv = bias[col];
#pragma unroll
    for (int mi = 0; mi < 4; mi++) {
      const int row = m0 + wr * 64 + mi * 16 + ((lane >> 4) << 2);
#pragma unroll
      for (int i = 0; i < 4; i++) {
        const float v = acc[mi][ni][i] + bv;
        if (OUT_BF16)
          ((__hip_bfloat16*)Cout)[(size_t)(row + i) * N + col] = __float2bfloat16(v);
        else
          ((float*)Cout)[(size_t)(row + i) * N + col] = v;
      }
    }
  }
}

// ---------------- neighborhood attention: lane-per-token ----------------
__global__ __launch_bounds__(256, 2) void natten(const __hip_bfloat16* __restrict__ qkv,
                                                 const float* __restrict__ rpb,
                                                 __hip_bfloat16* __restrict__ att) {
  __shared__ __align__(16) unsigned char smem[2 * WROWS * 128];  // K then V, swizzled

  const int tid = threadIdx.x;
  const int tb  = blockIdx.x;
  const int h   = blockIdx.y;
  const int b   = blockIdx.z;
  const int t0  = tb * TBLK;

  int r0 = t0 - NSH;
  if (r0 < 0) r0 = 0;
  if (r0 > LSEQ - WROWS) r0 = LSEQ - WROWS;

  const __hip_bfloat16* kg = qkv + ((size_t)b * LSEQ + r0) * QKV_N + DIMC + h * HEAD_DIM;
  const __hip_bfloat16* vg = kg + DIMC;
#pragma unroll 1
  for (int i = tid; i < WROWS * 8; i += 256) {
    const int row = i >> 3, c = i & 7;
    const uint4 kk = *(const uint4*)(kg + (size_t)row * QKV_N + c * 8);
    const uint4 vv = *(const uint4*)(vg + (size_t)row * QKV_N + c * 8);
    const int off = row * 128 + ((c * 16) ^ ((row & 7) << 4));
    *(uint4*)(smem + off) = kk;
    *(uint4*)(smem + WROWS * 128 + off) = vv;
  }
  __syncthreads();

  const int t = t0 + tid;
  int ni = t - NSH;
  ni = ni < 0 ? 0 : (ni > LSEQ - KWIN ? LSEQ - KWIN : ni);
  const int rbase = ni - r0;
  const int pi = NSH + (t < NSH ? NSH - t : 0) + (t + NSH >= LSEQ ? LSEQ - t - 1 - NSH : 0);
  const float* rp = rpb + h * (2 * KWIN - 1) + pi;

  const __hip_bfloat16* qg = qkv + ((size_t)b * LSEQ + t) * QKV_N + h * HEAD_DIM;
  float qf[64];
#pragma unroll
  for (int c = 0; c < 8; c++) {
    uint4 qq = *(const uint4*)(qg + c * 8);
    cvt8(qq, qf + c * 8);
  }

  float p[KWIN];
#pragma unroll
  for (int j = 0; j < KWIN; j++) {
    const int row = rbase + j;
    const int sw = (row & 7) << 4;
    float s = 0.f;
#pragma unroll
    for (int c = 0; c < 8; c++) {
      uint4 kk = *(const uint4*)(smem + row * 128 + ((c * 16) ^ sw));
      float kf[8];
      cvt8(kk, kf);
#pragma unroll
      for (int e = 0; e < 8; e++) s += qf[c * 8 + e] * kf[e];
    }
    p[j] = s * SCALE_Q + rp[j];
  }

  float m = p[0];
#pragma unroll
  for (int j = 1; j < KWIN; j++) m = fmaxf(m, p[j]);
  float sum = 0.f;
#pragma unroll
  for (int j = 0; j < KWIN; j++) { p[j] = __expf(p[j] - m); sum += p[j]; }
  const float inv = 1.f / sum;
#pragma unroll
  for (int j = 0; j < KWIN; j++) p[j] *= inv;

  __hip_bfloat16* og = att + ((size_t)b * LSEQ + t) * DIMC + h * HEAD_DIM;
#pragma unroll
  for (int c = 0; c < 8; c++) {
    float acc[8] = {0.f, 0.f, 0.f, 0.f, 0.f, 0.f, 0.f, 0.f};
#pragma unroll
    for (int j = 0; j < KWIN; j++) {
      const int row = rbase + j;
      uint4 vv = *(const uint4*)(smem + WROWS * 128 + row * 128 + ((c * 16) ^ ((row & 7) << 4)));
      float vf[8];
      cvt8(vv, vf);
#pragma unroll
      for (int e = 0; e < 8; e++) acc[e] += p[j] * vf[e];
    }
    union { ushort us[8]; uint4 v; } o;
#pragma unroll
    for (int e = 0; e < 8; e++) {
      __hip_bfloat16 hb = __float2bfloat16(acc[e]);
      o.us[e] = *(ushort*)&hb;
    }
    *(uint4*)(og + c * 8) = o.v;
  }
}

// ---------------- launch ----------------
extern "C" void kernel_launch(void* const* d_in, const int* in_sizes, int n_in,
                              void* d_out, int out_size, void* d_ws, size_t ws_size,
                              hipStream_t stream) {
  const float* x      = (const float*)d_in[0];
  const float* qkv_w  = (const float*)d_in[1];
  const float* qkv_b  = (const float*)d_in[2];
  const float* rpb    = (const float*)d_in[3];
  const float* proj_w = (const float*)d_in[4];
  const float* proj_b = (const float*)d_in[5];
  float* out = (float*)d_out;

  char* ws = (char*)d_ws;
  __hip_bfloat16* xb    = (__hip_bfloat16*)(ws);
  __hip_bfloat16* wqkv  = (__hip_bfloat16*)(ws + 16777216);
  __hip_bfloat16* wproj = (__hip_bfloat16*)(ws + 23068672);
  __hip_bfloat16* qkv   = (__hip_bfloat16*)(ws + 25165824);
  __hip_bfloat16* att   = (__hip_bfloat16*)(ws + 75497472);

  cast_kernel<<<(NROWS * DIMC / 4 + 255) / 256, 256, 0, stream>>>(x, xb, NROWS * DIMC / 4);
  cast_kernel<<<(QKV_N * DIMC / 4 + 255) / 256, 256, 0, stream>>>(qkv_w, wqkv, QKV_N * DIMC / 4);
  cast_kernel<<<(DIMC * DIMC / 4 + 255) / 256, 256, 0, stream>>>(proj_w, wproj, DIMC * DIMC / 4);

  gemm8<<<(NROWS / 256) * (QKV_N / 256), 512, 0, stream>>>(
      xb, wqkv, qkv_b, qkv, NROWS, QKV_N, DIMC);

  natten<<<dim3(LSEQ / TBLK, HEADS, BATCH), 256, 0, stream>>>(qkv, rpb, att);

  gemm_bt<0><<<dim3(DIMC / 128, NROWS / 128), 256, 0, stream>>>(
      att, wproj, proj_b, (void*)out, NROWS, DIMC, DIMC);
}

// Round 5
// 144.814 us; speedup vs baseline: 1.4037x; 1.3985x over previous
//
#include <hip/hip_runtime.h>
#include <hip/hip_bf16.h>

// Problem constants (fixed by reference)
#define DIMC 1024
#define HEADS 16
#define HEAD_DIM 64
#define KWIN 13
#define NSH 6
#define LSEQ 4096
#define BATCH 2
#define NROWS (BATCH*LSEQ)        // 8192 token rows
#define QKV_N (3*DIMC)            // 3072
#define SCALE_Q 0.125f            // 64^-0.5

#define TBLK 256                  // tokens per natten block
#define WROWS 268                 // staged K/V window rows (256 + 12)

typedef __attribute__((ext_vector_type(4))) float f32x4;
typedef __attribute__((ext_vector_type(8))) short bf16x8;

__device__ __forceinline__ void gload_lds16(const void* g, void* l) {
  __builtin_amdgcn_global_load_lds(
      (const __attribute__((address_space(1))) void*)g,
      (__attribute__((address_space(3))) void*)l, 16, 0, 0);
}

// unpack 8 bf16 (in uint4) -> 8 f32
__device__ __forceinline__ void cvt8(uint4 r, float* f) {
  unsigned u[4] = {r.x, r.y, r.z, r.w};
#pragma unroll
  for (int w = 0; w < 4; w++) {
    f[2*w]   = __uint_as_float(u[w] << 16);
    f[2*w+1] = __uint_as_float(u[w] & 0xffff0000u);
  }
}

// ---------------- cast fp32 -> bf16 (vectorized) ----------------
__global__ __launch_bounds__(256) void cast_kernel(const float* __restrict__ in,
                                                   __hip_bfloat16* __restrict__ out,
                                                   int n4) {
  int i = blockIdx.x * 256 + threadIdx.x;
  if (i >= n4) return;
  float4 v = ((const float4*)in)[i];
  union { short4 s; __hip_bfloat16 h[4]; } u;
  u.h[0] = __float2bfloat16(v.x);
  u.h[1] = __float2bfloat16(v.y);
  u.h[2] = __float2bfloat16(v.z);
  u.h[3] = __float2bfloat16(v.w);
  ((short4*)out)[i] = u.s;
}

// ---------------- bf16 GEMM: C[M][N] = A[M][K] * B[N][K]^T + bias ----------------
// 128x128 tile, BK=32, 256 threads (4 waves, 2x2 wave grid of 64x64 subtiles),
// global_load_lds width=16 staging, mfma_f32_16x16x32_bf16.
// LDS chunk-XOR swizzle (perm(row) = (row>>1)&3): pre-permuted GLOBAL source
// (LDS dest stays linear, rule #21) + same XOR on fragment reads.
// Bank math: lanes 0-15 (rows r..r+15) now cover 8 distinct bank-quads at
// 2 lanes/bank (free, m136) instead of 8-way on banks {0,16}.
template<int OUT_BF16>
__global__ __launch_bounds__(256) void gemm_bt(const __hip_bfloat16* __restrict__ A,
                                               const __hip_bfloat16* __restrict__ B,
                                               const float* __restrict__ bias,
                                               void* __restrict__ Cout,
                                               int M, int N, int K) {
  __shared__ __align__(16) __hip_bfloat16 As[128 * 32];
  __shared__ __align__(16) __hip_bfloat16 Bs[128 * 32];

  const int tid  = threadIdx.x;
  const int lane = tid & 63;
  const int wave = tid >> 6;
  const int m0 = blockIdx.y * 128;
  const int n0 = blockIdx.x * 128;
  const int wr = wave >> 1;
  const int wc = wave & 1;

  f32x4 acc[4][4] = {};

  // staging: call c covers rows wave*32 + c*16 + (lane>>2); 4 lanes/row,
  // LDS chunk (lane&3) <- global chunk (lane&3) ^ perm(row), perm=(row>>1)&3
  // = (lane>>3)&3 here (wave*32, c*16 are multiples of 8 rows).
  const int rA0  = wave * 32 + (lane >> 2);
  const int kcol = ((lane & 3) ^ ((lane >> 3) & 3)) * 8;
  const __hip_bfloat16* gA = A + (size_t)(m0 + rA0) * K + kcol;
  const __hip_bfloat16* gB = B + (size_t)(n0 + rA0) * K + kcol;
  __hip_bfloat16* lA0 = As + wave * 1024;
  __hip_bfloat16* lA1 = As + wave * 1024 + 512;
  __hip_bfloat16* lB0 = Bs + wave * 1024;
  __hip_bfloat16* lB1 = Bs + wave * 1024 + 512;

  // fragment read: row = base + fr (base multiple of 16), wants global chunk
  // fkc = lane>>4 -> read LDS chunk fkc ^ perm(row), perm = (fr>>1)&3.
  const int fr  = lane & 15;
  const int fk0 = (((lane >> 4) ^ ((fr >> 1) & 3)) & 3) * 8;

  for (int k0 = 0; k0 < K; k0 += 32) {
    gload_lds16(gA,                  lA0);
    gload_lds16(gA + (size_t)16 * K, lA1);
    gload_lds16(gB,                  lB0);
    gload_lds16(gB + (size_t)16 * K, lB1);
    gA += 32;
    gB += 32;
    __syncthreads();

    bf16x8 af[4], bfr[4];
#pragma unroll
    for (int i = 0; i < 4; i++)
      af[i] = *(const bf16x8*)&As[(wr * 64 + i * 16 + fr) * 32 + fk0];
#pragma unroll
    for (int i = 0; i < 4; i++)
      bfr[i] = *(const bf16x8*)&Bs[(wc * 64 + i * 16 + fr) * 32 + fk0];

#pragma unroll
    for (int mi = 0; mi < 4; mi++)
#pragma unroll
      for (int ni = 0; ni < 4; ni++)
        acc[mi][ni] = __builtin_amdgcn_mfma_f32_16x16x32_bf16(af[mi], bfr[ni], acc[mi][ni], 0, 0, 0);

    __syncthreads();
  }

  // epilogue: C/D layout col = lane&15, row = (lane>>4)*4 + reg
#pragma unroll
  for (int ni = 0; ni < 4; ni++) {
    const int col = n0 + wc * 64 + ni * 16 + (lane & 15);
    const float bv = bias[col];
#pragma unroll
    for (int mi = 0; mi < 4; mi++) {
      const int row = m0 + wr * 64 + mi * 16 + ((lane >> 4) << 2);
#pragma unroll
      for (int i = 0; i < 4; i++) {
        const float v = acc[mi][ni][i] + bv;
        if (OUT_BF16)
          ((__hip_bfloat16*)Cout)[(size_t)(row + i) * N + col] = __float2bfloat16(v);
        else
          ((float*)Cout)[(size_t)(row + i) * N + col] = v;
      }
    }
  }
}

// ---------------- neighborhood attention: lane-per-token ----------------
// block = 256 threads = 256 tokens of one (b,h). K/V window staged in LDS
// with XOR swizzle; softmax entirely lane-local (no shuffles).
__global__ __launch_bounds__(256, 2) void natten(const __hip_bfloat16* __restrict__ qkv,
                                                 const float* __restrict__ rpb,
                                                 __hip_bfloat16* __restrict__ att) {
  __shared__ __align__(16) unsigned char smem[2 * WROWS * 128];  // K then V, swizzled

  const int tid = threadIdx.x;
  const int tb  = blockIdx.x;
  const int h   = blockIdx.y;
  const int b   = blockIdx.z;
  const int t0  = tb * TBLK;

  int r0 = t0 - NSH;
  if (r0 < 0) r0 = 0;
  if (r0 > LSEQ - WROWS) r0 = LSEQ - WROWS;

  const __hip_bfloat16* kg = qkv + ((size_t)b * LSEQ + r0) * QKV_N + DIMC + h * HEAD_DIM;
  const __hip_bfloat16* vg = kg + DIMC;
#pragma unroll 1
  for (int i = tid; i < WROWS * 8; i += 256) {
    const int row = i >> 3, c = i & 7;
    const uint4 kk = *(const uint4*)(kg + (size_t)row * QKV_N + c * 8);
    const uint4 vv = *(const uint4*)(vg + (size_t)row * QKV_N + c * 8);
    const int off = row * 128 + ((c * 16) ^ ((row & 7) << 4));
    *(uint4*)(smem + off) = kk;
    *(uint4*)(smem + WROWS * 128 + off) = vv;
  }
  __syncthreads();

  const int t = t0 + tid;
  int ni = t - NSH;
  ni = ni < 0 ? 0 : (ni > LSEQ - KWIN ? LSEQ - KWIN : ni);
  const int rbase = ni - r0;
  const int pi = NSH + (t < NSH ? NSH - t : 0) + (t + NSH >= LSEQ ? LSEQ - t - 1 - NSH : 0);
  const float* rp = rpb + h * (2 * KWIN - 1) + pi;

  const __hip_bfloat16* qg = qkv + ((size_t)b * LSEQ + t) * QKV_N + h * HEAD_DIM;
  float qf[64];
#pragma unroll
  for (int c = 0; c < 8; c++) {
    uint4 qq = *(const uint4*)(qg + c * 8);
    cvt8(qq, qf + c * 8);
  }

  float p[KWIN];
#pragma unroll
  for (int j = 0; j < KWIN; j++) {
    const int row = rbase + j;
    const int sw = (row & 7) << 4;
    float s = 0.f;
#pragma unroll
    for (int c = 0; c < 8; c++) {
      uint4 kk = *(const uint4*)(smem + row * 128 + ((c * 16) ^ sw));
      float kf[8];
      cvt8(kk, kf);
#pragma unroll
      for (int e = 0; e < 8; e++) s += qf[c * 8 + e] * kf[e];
    }
    p[j] = s * SCALE_Q + rp[j];
  }

  float m = p[0];
#pragma unroll
  for (int j = 1; j < KWIN; j++) m = fmaxf(m, p[j]);
  float sum = 0.f;
#pragma unroll
  for (int j = 0; j < KWIN; j++) { p[j] = __expf(p[j] - m); sum += p[j]; }
  const float inv = 1.f / sum;
#pragma unroll
  for (int j = 0; j < KWIN; j++) p[j] *= inv;

  __hip_bfloat16* og = att + ((size_t)b * LSEQ + t) * DIMC + h * HEAD_DIM;
#pragma unroll
  for (int c = 0; c < 8; c++) {
    float acc[8] = {0.f, 0.f, 0.f, 0.f, 0.f, 0.f, 0.f, 0.f};
#pragma unroll
    for (int j = 0; j < KWIN; j++) {
      const int row = rbase + j;
      uint4 vv = *(const uint4*)(smem + WROWS * 128 + row * 128 + ((c * 16) ^ ((row & 7) << 4)));
      float vf[8];
      cvt8(vv, vf);
#pragma unroll
      for (int e = 0; e < 8; e++) acc[e] += p[j] * vf[e];
    }
    union { ushort us[8]; uint4 v; } o;
#pragma unroll
    for (int e = 0; e < 8; e++) {
      __hip_bfloat16 hb = __float2bfloat16(acc[e]);
      o.us[e] = *(ushort*)&hb;
    }
    *(uint4*)(og + c * 8) = o.v;
  }
}

// ---------------- launch ----------------
extern "C" void kernel_launch(void* const* d_in, const int* in_sizes, int n_in,
                              void* d_out, int out_size, void* d_ws, size_t ws_size,
                              hipStream_t stream) {
  const float* x      = (const float*)d_in[0];
  const float* qkv_w  = (const float*)d_in[1];
  const float* qkv_b  = (const float*)d_in[2];
  const float* rpb    = (const float*)d_in[3];
  const float* proj_w = (const float*)d_in[4];
  const float* proj_b = (const float*)d_in[5];
  float* out = (float*)d_out;

  char* ws = (char*)d_ws;
  __hip_bfloat16* xb    = (__hip_bfloat16*)(ws);
  __hip_bfloat16* wqkv  = (__hip_bfloat16*)(ws + 16777216);
  __hip_bfloat16* wproj = (__hip_bfloat16*)(ws + 23068672);
  __hip_bfloat16* qkv   = (__hip_bfloat16*)(ws + 25165824);
  __hip_bfloat16* att   = (__hip_bfloat16*)(ws + 75497472);

  cast_kernel<<<(NROWS * DIMC / 4 + 255) / 256, 256, 0, stream>>>(x, xb, NROWS * DIMC / 4);
  cast_kernel<<<(QKV_N * DIMC / 4 + 255) / 256, 256, 0, stream>>>(qkv_w, wqkv, QKV_N * DIMC / 4);
  cast_kernel<<<(DIMC * DIMC / 4 + 255) / 256, 256, 0, stream>>>(proj_w, wproj, DIMC * DIMC / 4);

  gemm_bt<1><<<dim3(QKV_N / 128, NROWS / 128), 256, 0, stream>>>(
      xb, wqkv, qkv_b, (void*)qkv, NROWS, QKV_N, DIMC);

  natten<<<dim3(LSEQ / TBLK, HEADS, BATCH), 256, 0, stream>>>(qkv, rpb, att);

  gemm_bt<0><<<dim3(DIMC / 128, NROWS / 128), 256, 0, stream>>>(
      att, wproj, proj_b, (void*)out, NROWS, DIMC, DIMC);
}